// Round 8
// baseline (353.028 us; speedup 1.0000x reference)
//
#include <hip/hip_runtime.h>

using bf16x8 = __attribute__((ext_vector_type(8))) __bf16;
using f32x4  = __attribute__((ext_vector_type(4))) float;
using f32x16 = __attribute__((ext_vector_type(16))) float;
typedef __attribute__((ext_vector_type(4))) unsigned u32x4;

#define DEV __device__ __forceinline__

DEV unsigned short f2bf(float f){
  unsigned u = __builtin_bit_cast(unsigned, f);
  u += 0x7fffu + ((u >> 16) & 1u);
  return (unsigned short)(u >> 16);
}

DEV void load_lds16(const void* g, void* l){
  __builtin_amdgcn_global_load_lds((const __attribute__((address_space(1))) unsigned*)g,
                                   (__attribute__((address_space(3))) unsigned*)l, 16, 0, 0);
}

DEV f32x4 mfma16(bf16x8 a, bf16x8 b, f32x4 c){
  return __builtin_amdgcn_mfma_f32_16x16x32_bf16(a, b, c, 0, 0, 0);
}

DEV f32x16 mfma32(bf16x8 a, bf16x8 b, f32x16 c){
  return __builtin_amdgcn_mfma_f32_32x32x16_bf16(a, b, c, 0, 0, 0);
}

DEV float exp2_hw(float x){
  float r;
  asm("v_exp_f32 %0, %1" : "=v"(r) : "v"(x));
  return r;
}

DEV unsigned cvtpk_bf16(float a, float b){
  unsigned r;
  asm("v_cvt_pk_bf16_f32 %0, %1, %2" : "=v"(r) : "v"(a), "v"(b));
  return r;
}

DEV void permswap(unsigned &a, unsigned &b){
  asm volatile("v_permlane32_swap_b32 %0, %1" : "+v"(a), "+v"(b));
}

// ---------------- weight fp32 -> bf16 ----------------
__global__ void wconv_k(const float* __restrict__ a, unsigned short* __restrict__ o, int n4){
  for (int i = blockIdx.x * blockDim.x + threadIdx.x; i < n4; i += gridDim.x * blockDim.x){
    float4 v = reinterpret_cast<const float4*>(a)[i];
    ushort4 u;
    u.x = f2bf(v.x); u.y = f2bf(v.y); u.z = f2bf(v.z); u.w = f2bf(v.w);
    reinterpret_cast<ushort4*>(o)[i] = u;
  }
}

// ---------------- GroupNorm stats ----------------
__global__ __launch_bounds__(256) void gn_stats_k(const float* __restrict__ x, float* __restrict__ st){
  int bg = blockIdx.x; // b*32+g
  const float4* xp = reinterpret_cast<const float4*>(x + (size_t)bg * 32768);
  float s = 0.f, ss = 0.f;
  for (int i = threadIdx.x; i < 8192; i += 256){
    float4 v = xp[i];
    s  += (v.x + v.y) + (v.z + v.w);
    ss += (v.x*v.x + v.y*v.y) + (v.z*v.z + v.w*v.w);
  }
  #pragma unroll
  for (int off = 32; off; off >>= 1){ s += __shfl_down(s, off); ss += __shfl_down(ss, off); }
  __shared__ float rs[4], rss[4];
  if ((threadIdx.x & 63) == 0){ rs[threadIdx.x >> 6] = s; rss[threadIdx.x >> 6] = ss; }
  __syncthreads();
  if (threadIdx.x == 0){
    s  = (rs[0] + rs[1]) + (rs[2] + rs[3]);
    ss = (rss[0] + rss[1]) + (rss[2] + rss[3]);
    float mu  = s * (1.0f / 32768.0f);
    float var = ss * (1.0f / 32768.0f) - mu * mu;
    st[bg*2]   = mu;
    st[bg*2+1] = rsqrtf(var + 1e-5f);
  }
}

// ---------------- GN apply ----------------
__global__ __launch_bounds__(256) void gn_norm_k(const float* __restrict__ x,
                                                 const float* __restrict__ gw,
                                                 const float* __restrict__ gb,
                                                 const float* __restrict__ st,
                                                 float* __restrict__ xn,
                                                 unsigned short* __restrict__ xnt){
  int t = blockIdx.x;            // B*G*16 = 4096
  int tile = t & 15; int g = (t >> 4) & 31; int bb = t >> 9;
  float mu = st[(bb*32+g)*2], rstd = st[(bb*32+g)*2+1];
  __shared__ unsigned short lt[64*32];
  int tid = threadIdx.x;
  int l = tid & 63;
  int c0 = tid >> 6;
  size_t base = ((size_t)bb*1024 + g*32) * 1024 + tile*64;
  #pragma unroll
  for (int cb = 0; cb < 8; ++cb){
    int c = cb*4 + c0;
    size_t idx = base + (size_t)c*1024 + l;
    float xv = x[idx];
    int cg = g*32 + c;
    float v = (xv - mu) * rstd * gw[cg] + gb[cg];
    xn[idx] = v;
    lt[l*32 + c] = f2bf(v);
  }
  __syncthreads();
  int lr = tid >> 2, sl = tid & 3;
  uint4 u = *reinterpret_cast<uint4*>(&lt[lr*32 + sl*8]);
  size_t ob = ((size_t)bb*1024 + tile*64 + lr) * 1024 + g*32 + sl*8;
  *reinterpret_cast<uint4*>(&xnt[ob]) = u;
}

// ---------------- GEMM (r3-proven 2-phase 128x128): C = A[M][K] * Bt[N][K]^T ----------------
template<int MODE>
__global__ __launch_bounds__(256) void gemm_k(const unsigned short* __restrict__ A,
                                              const unsigned short* __restrict__ Bm,
                                              const float* __restrict__ bias,
                                              float* __restrict__ outf,
                                              unsigned short* __restrict__ qo,
                                              unsigned short* __restrict__ ko,
                                              unsigned short* __restrict__ vo){
  constexpr int MT = MODE ? 8 : 24;
  constexpr int CHUNK = MT * 8;
  __shared__ char sA[16384];
  __shared__ char sB[16384];
  const int tid = threadIdx.x;
  const int w = tid >> 6, ln = tid & 63, hi = ln >> 4, lo = ln & 15;
  const int wrow = w >> 1, wcol = w & 1;
  const int bxo = (int)blockIdx.x;
  const int bx = (bxo & 7) * CHUNK + (bxo >> 3);
  const int b = bx / (MT*8);
  const int rem = bx % (MT*8);
  const int mt = rem >> 3, nt = rem & 7;
  const char* Ag = (const char*)A + (size_t)mt*128*2048;
  const char* Bg = (const char*)Bm + ((size_t)b*1024 + nt*128)*2048;
  f32x4 acc[4][4] = {};
  for (int kk = 0; kk < 16; ++kk){
    #pragma unroll
    for (int i = 0; i < 4; ++i){
      int s = tid*16 + i*4096;
      int row = s >> 7;
      int byte = (s & 127) ^ ((row & 7) << 4);
      size_t off = (size_t)row*2048 + kk*128 + byte;
      load_lds16(Ag + off, sA + s);
      load_lds16(Bg + off, sB + s);
    }
    __syncthreads();
    #pragma unroll
    for (int ks = 0; ks < 2; ++ks){
      bf16x8 af[4], bq[4];
      #pragma unroll
      for (int mi = 0; mi < 4; ++mi){
        int row = wrow*64 + mi*16 + lo;
        af[mi] = *reinterpret_cast<const bf16x8*>(sA + row*128 + ((ks*64 + hi*16) ^ ((row & 7) << 4)));
      }
      #pragma unroll
      for (int ni = 0; ni < 4; ++ni){
        int row = wcol*64 + ni*16 + lo;
        bq[ni] = *reinterpret_cast<const bf16x8*>(sB + row*128 + ((ks*64 + hi*16) ^ ((row & 7) << 4)));
      }
      #pragma unroll
      for (int mi = 0; mi < 4; ++mi)
        #pragma unroll
        for (int ni = 0; ni < 4; ++ni)
          acc[mi][ni] = mfma16(af[mi], bq[ni], acc[mi][ni]);
    }
    __syncthreads();
  }
  if (MODE == 0){
    #pragma unroll
    for (int mi = 0; mi < 4; ++mi){
      const int o0 = mt*128 + wrow*64 + mi*16 + hi*4;
      const int hh = o0 / 192;
      const int rr = o0 % 192;
      const size_t hb = (size_t)b*16 + hh;
      float bv0 = bias[o0], bv1 = bias[o0+1], bv2 = bias[o0+2], bv3 = bias[o0+3];
      #pragma unroll
      for (int ni = 0; ni < 4; ++ni){
        const int l = nt*128 + wcol*64 + ni*16 + lo;
        if (rr < 64){
          ushort4 u;
          u.x = f2bf(acc[mi][ni][0] + bv0); u.y = f2bf(acc[mi][ni][1] + bv1);
          u.z = f2bf(acc[mi][ni][2] + bv2); u.w = f2bf(acc[mi][ni][3] + bv3);
          *reinterpret_cast<ushort4*>(qo + (hb*1024 + l)*64 + rr) = u;
        } else if (rr < 128){
          ushort4 u;
          u.x = f2bf(acc[mi][ni][0] + bv0); u.y = f2bf(acc[mi][ni][1] + bv1);
          u.z = f2bf(acc[mi][ni][2] + bv2); u.w = f2bf(acc[mi][ni][3] + bv3);
          *reinterpret_cast<ushort4*>(ko + (hb*1024 + l)*64 + (rr - 64)) = u;
        } else {
          const int d = rr - 128;
          vo[(hb*64 + d + 0)*1024 + l] = f2bf(acc[mi][ni][0] + bv0);
          vo[(hb*64 + d + 1)*1024 + l] = f2bf(acc[mi][ni][1] + bv1);
          vo[(hb*64 + d + 2)*1024 + l] = f2bf(acc[mi][ni][2] + bv2);
          vo[(hb*64 + d + 3)*1024 + l] = f2bf(acc[mi][ni][3] + bv3);
        }
      }
    }
  } else {
    #pragma unroll
    for (int mi = 0; mi < 4; ++mi){
      const int o0 = mt*128 + wrow*64 + mi*16 + hi*4;
      #pragma unroll
      for (int ni = 0; ni < 4; ++ni){
        const int l = nt*128 + wcol*64 + ni*16 + lo;
        #pragma unroll
        for (int r = 0; r < 4; ++r){
          size_t idx = ((size_t)b*1024 + o0 + r) * 1024 + l;
          outf[idx] += acc[mi][ni][r] + bias[o0 + r];
        }
      }
    }
  }
}

// ---------------- flash attention v4: barrier-free, K/V direct from global (L1/L2) ----------------
// Same swapped-QK^T 32x32 fragment algebra as r3 (validated), but no LDS staging:
// K frag: lane(hi5,lo5) reads K[kb*64 + {lo5,32+lo5}][d*32+hi5*16 ..+16]  (row = 128B line)
// V frag: lane reads V[d={lo5,32+lo5}][kb*128B + sl*32+hi5*16 ..+16]      (line-utilizing)
// Waves fully independent -> no s_barrier, no vmcnt drains; LDS = 512B (epilogue redistribute).
__global__ __launch_bounds__(256) void attn_k(const unsigned short* __restrict__ qt,
                                              const unsigned short* __restrict__ kt,
                                              const unsigned short* __restrict__ vt,
                                              unsigned short* __restrict__ ctx){
  __shared__ float sRed[4][32];
  const int tid = threadIdx.x;
  const int w = tid >> 6, ln = tid & 63;
  const int hi5 = ln >> 5, lo5 = ln & 31;
  const int bxo = (int)blockIdx.x;
  const int bx = (bxo & 7) * 128 + (bxo >> 3);   // XCD swizzle: 16 heads per XCD
  const int qb = bx & 7;
  const int bh = bx >> 3;                        // b*16 + h
  const unsigned short* qp = qt + ((size_t)bh*1024 + qb*128 + w*32 + lo5) * 64;
  bf16x8 qreg[4];
  #pragma unroll
  for (int d = 0; d < 4; ++d)
    qreg[d] = *reinterpret_cast<const bf16x8*>(qp + d*16 + hi5*8);
  const char* kg = (const char*)(kt + (size_t)bh*65536);
  const char* vg = (const char*)(vt + (size_t)bh*65536);
  f32x16 oa0 = {}, oa1 = {};
  float m = 0.f, l = 0.f;

  const float sc2 = 0.015625f * 1.44269504f;  // (1/64) * log2(e)

  for (int kb = 0; kb < 16; ++kb){
    // --- QK^T swapped: s0 = S[k=0..31][q=lo5], s1 = S[k=32..63][q=lo5] ---
    const char* kr0 = kg + (size_t)(kb*64 + lo5)*128;
    const char* kr1 = kg + (size_t)(kb*64 + 32 + lo5)*128;
    f32x16 s0 = {}, s1 = {};
    #pragma unroll
    for (int d = 0; d < 4; ++d){
      int off = d*32 + hi5*16;
      bf16x8 ka  = *reinterpret_cast<const bf16x8*>(kr0 + off);
      bf16x8 kb8 = *reinterpret_cast<const bf16x8*>(kr1 + off);
      s0 = mfma32(ka, qreg[d], s0);
      s1 = mfma32(kb8, qreg[d], s1);
    }

    // --- row max: lane-local tree + one cross-half shuffle ---
    float t[16];
    #pragma unroll
    for (int i = 0; i < 16; ++i) t[i] = fmaxf(s0[i], s1[i]);
    #pragma unroll
    for (int st = 8; st; st >>= 1)
      #pragma unroll
      for (int i = 0; i < st; ++i) t[i] = fmaxf(t[i], t[i+st]);
    float mx = fmaxf(t[0], __shfl_xor(t[0], 32));
    float m2 = mx * sc2;

    // --- defer-max (T13): cold path, redistribute corr via LDS (per-wave slice) ---
    if (__builtin_expect(__any(m2 > m + 8.f), 0)){
      float nm = fmaxf(m, m2);
      float corr = exp2_hw(m - nm);
      m = nm; l *= corr;
      sRed[w][lo5] = corr;
      __builtin_amdgcn_wave_barrier();
      #pragma unroll
      for (int r = 0; r < 16; ++r){
        float cc = sRed[w][(r & 3) + 8*(r >> 2) + 4*hi5];
        oa0[r] *= cc; oa1[r] *= cc;
      }
      __builtin_amdgcn_wave_barrier();
    }

    // --- P = 2^(S*sc2 - m), lane-local sum tree ---
    float ps[16];
    #pragma unroll
    for (int i = 0; i < 16; ++i){
      float p0 = exp2_hw(fmaf(s0[i], sc2, -m));
      float p1 = exp2_hw(fmaf(s1[i], sc2, -m));
      s0[i] = p0; s1[i] = p1;
      ps[i] = p0 + p1;
    }
    #pragma unroll
    for (int st = 8; st; st >>= 1)
      #pragma unroll
      for (int i = 0; i < st; ++i) ps[i] += ps[i+st];
    l += ps[0] + __shfl_xor(ps[0], 32);

    // --- P -> PV A-frags: cvt_pk pairs + permlane32_swap (T12) ---
    bf16x8 pa[4];
    #pragma unroll
    for (int sl = 0; sl < 4; ++sl){
      const int c0 = 2*(sl & 1), c1 = c0 + 1;
      unsigned w0, w1, w2, w3;
      if (sl < 2){
        w0 = cvtpk_bf16(s0[4*c0+0], s0[4*c0+1]);
        w1 = cvtpk_bf16(s0[4*c0+2], s0[4*c0+3]);
        w2 = cvtpk_bf16(s0[4*c1+0], s0[4*c1+1]);
        w3 = cvtpk_bf16(s0[4*c1+2], s0[4*c1+3]);
      } else {
        w0 = cvtpk_bf16(s1[4*c0+0], s1[4*c0+1]);
        w1 = cvtpk_bf16(s1[4*c0+2], s1[4*c0+3]);
        w2 = cvtpk_bf16(s1[4*c1+0], s1[4*c1+1]);
        w3 = cvtpk_bf16(s1[4*c1+2], s1[4*c1+3]);
      }
      permswap(w0, w2);
      permswap(w1, w3);
      u32x4 pc; pc.x = w0; pc.y = w1; pc.z = w2; pc.w = w3;
      pa[sl] = __builtin_bit_cast(bf16x8, pc);
    }

    // --- PV: O[q][d], d = dblk*32 + lo5; V rows direct from global ---
    const char* vr0 = vg + (size_t)lo5*2048 + kb*128;
    const char* vr1 = vg + (size_t)(32 + lo5)*2048 + kb*128;
    #pragma unroll
    for (int sl = 0; sl < 4; ++sl){
      int off = sl*32 + hi5*16;
      bf16x8 v0 = *reinterpret_cast<const bf16x8*>(vr0 + off);
      bf16x8 v1 = *reinterpret_cast<const bf16x8*>(vr1 + off);
      oa0 = mfma32(pa[sl], v0, oa0);
      oa1 = mfma32(pa[sl], v1, oa1);
    }
  }

  // --- epilogue: redistribute l across the wave, write ctx^T [b][l][c] ---
  sRed[w][lo5] = l;
  __builtin_amdgcn_wave_barrier();
  const int b = bh >> 4, h = bh & 15;
  #pragma unroll
  for (int r = 0; r < 16; ++r){
    int ql = (r & 3) + 8*(r >> 2) + 4*hi5;
    float inv = __builtin_amdgcn_rcpf(sRed[w][ql]);
    size_t rowb = ((size_t)b*1024 + qb*128 + w*32 + ql) * 1024 + h*64;
    ctx[rowb + lo5]      = f2bf(oa0[r] * inv);
    ctx[rowb + 32 + lo5] = f2bf(oa1[r] * inv);
  }
}

extern "C" void kernel_launch(void* const* d_in, const int* in_sizes, int n_in,
                              void* d_out, int out_size, void* d_ws, size_t ws_size,
                              hipStream_t stream) {
  (void)in_sizes; (void)n_in; (void)out_size; (void)ws_size;
  const float* x     = (const float*)d_in[0];
  const float* gn_w  = (const float*)d_in[1];
  const float* gn_b  = (const float*)d_in[2];
  const float* qkv_w = (const float*)d_in[3];
  const float* qkv_b = (const float*)d_in[4];
  const float* out_w = (const float*)d_in[5];
  const float* out_b = (const float*)d_in[6];
  // d_in[7] = qk_bias scalar: softmax(x+c)==softmax(x) -> no-op.
  float* out = (float*)d_out;
  char* ws = (char*)d_ws;
  unsigned short* xnt  = (unsigned short*)(ws);               // 16 MiB  xn^T  [b][l][c]
  unsigned short* qwb  = (unsigned short*)(ws + 16777216);    // 6 MiB   qkv_w bf16
  unsigned short* owb  = (unsigned short*)(ws + 23068672);    // 2 MiB   out_w bf16
  unsigned short* qt   = (unsigned short*)(ws + 25165824);    // 16 MiB  q [b][h][l][d]
  unsigned short* kt   = (unsigned short*)(ws + 41943040);    // 16 MiB  k [b][h][l][d]
  unsigned short* vs   = (unsigned short*)(ws + 58720256);    // 16 MiB  v [b][h][d][l]
  unsigned short* ctxt = (unsigned short*)(ws + 75497472);    // 16 MiB  ctx^T [b][l][c]
  float*          st   = (float*)(ws + 92274688);             // 2 KiB   GN stats

  wconv_k<<<512, 256, 0, stream>>>(qkv_w, qwb, 786432);
  wconv_k<<<512, 256, 0, stream>>>(out_w, owb, 262144);
  gn_stats_k<<<256, 256, 0, stream>>>(x, st);
  gn_norm_k<<<4096, 256, 0, stream>>>(x, gn_w, gn_b, st, out, xnt);
  gemm_k<0><<<1536, 256, 0, stream>>>(qwb, xnt, qkv_b, nullptr, qt, kt, vs);
  attn_k<<<1024, 256, 0, stream>>>(qt, kt, vs, ctxt);
  gemm_k<1><<<512, 256, 0, stream>>>(owb, ctxt, out_b, out, nullptr, nullptr, nullptr);
}

// Round 9
// 280.971 us; speedup vs baseline: 1.2565x; 1.2565x over previous
//
#include <hip/hip_runtime.h>

using bf16x8 = __attribute__((ext_vector_type(8))) __bf16;
using f32x4  = __attribute__((ext_vector_type(4))) float;
using f32x16 = __attribute__((ext_vector_type(16))) float;
typedef __attribute__((ext_vector_type(4))) unsigned u32x4;

#define DEV __device__ __forceinline__

DEV unsigned short f2bf(float f){
  unsigned u = __builtin_bit_cast(unsigned, f);
  u += 0x7fffu + ((u >> 16) & 1u);
  return (unsigned short)(u >> 16);
}

DEV void load_lds16(const void* g, void* l){
  __builtin_amdgcn_global_load_lds((const __attribute__((address_space(1))) unsigned*)g,
                                   (__attribute__((address_space(3))) unsigned*)l, 16, 0, 0);
}

DEV f32x4 mfma16(bf16x8 a, bf16x8 b, f32x4 c){
  return __builtin_amdgcn_mfma_f32_16x16x32_bf16(a, b, c, 0, 0, 0);
}

DEV f32x16 mfma32(bf16x8 a, bf16x8 b, f32x16 c){
  return __builtin_amdgcn_mfma_f32_32x32x16_bf16(a, b, c, 0, 0, 0);
}

DEV float exp2_hw(float x){
  float r;
  asm("v_exp_f32 %0, %1" : "=v"(r) : "v"(x));
  return r;
}

DEV unsigned cvtpk_bf16(float a, float b){
  unsigned r;
  asm("v_cvt_pk_bf16_f32 %0, %1, %2" : "=v"(r) : "v"(a), "v"(b));
  return r;
}

DEV void permswap(unsigned &a, unsigned &b){
  asm volatile("v_permlane32_swap_b32 %0, %1" : "+v"(a), "+v"(b));
}

// ---------------- weight fp32 -> bf16 ----------------
__global__ void wconv_k(const float* __restrict__ a, unsigned short* __restrict__ o, int n4){
  for (int i = blockIdx.x * blockDim.x + threadIdx.x; i < n4; i += gridDim.x * blockDim.x){
    float4 v = reinterpret_cast<const float4*>(a)[i];
    ushort4 u;
    u.x = f2bf(v.x); u.y = f2bf(v.y); u.z = f2bf(v.z); u.w = f2bf(v.w);
    reinterpret_cast<ushort4*>(o)[i] = u;
  }
}

// ---------------- GroupNorm stats ----------------
__global__ __launch_bounds__(256) void gn_stats_k(const float* __restrict__ x, float* __restrict__ st){
  int bg = blockIdx.x; // b*32+g
  const float4* xp = reinterpret_cast<const float4*>(x + (size_t)bg * 32768);
  float s = 0.f, ss = 0.f;
  for (int i = threadIdx.x; i < 8192; i += 256){
    float4 v = xp[i];
    s  += (v.x + v.y) + (v.z + v.w);
    ss += (v.x*v.x + v.y*v.y) + (v.z*v.z + v.w*v.w);
  }
  #pragma unroll
  for (int off = 32; off; off >>= 1){ s += __shfl_down(s, off); ss += __shfl_down(ss, off); }
  __shared__ float rs[4], rss[4];
  if ((threadIdx.x & 63) == 0){ rs[threadIdx.x >> 6] = s; rss[threadIdx.x >> 6] = ss; }
  __syncthreads();
  if (threadIdx.x == 0){
    s  = (rs[0] + rs[1]) + (rs[2] + rs[3]);
    ss = (rss[0] + rss[1]) + (rss[2] + rss[3]);
    float mu  = s * (1.0f / 32768.0f);
    float var = ss * (1.0f / 32768.0f) - mu * mu;
    st[bg*2]   = mu;
    st[bg*2+1] = rsqrtf(var + 1e-5f);
  }
}

// ---------------- GN apply ----------------
__global__ __launch_bounds__(256) void gn_norm_k(const float* __restrict__ x,
                                                 const float* __restrict__ gw,
                                                 const float* __restrict__ gb,
                                                 const float* __restrict__ st,
                                                 float* __restrict__ xn,
                                                 unsigned short* __restrict__ xnt){
  int t = blockIdx.x;            // B*G*16 = 4096
  int tile = t & 15; int g = (t >> 4) & 31; int bb = t >> 9;
  float mu = st[(bb*32+g)*2], rstd = st[(bb*32+g)*2+1];
  __shared__ unsigned short lt[64*32];
  int tid = threadIdx.x;
  int l = tid & 63;
  int c0 = tid >> 6;
  size_t base = ((size_t)bb*1024 + g*32) * 1024 + tile*64;
  #pragma unroll
  for (int cb = 0; cb < 8; ++cb){
    int c = cb*4 + c0;
    size_t idx = base + (size_t)c*1024 + l;
    float xv = x[idx];
    int cg = g*32 + c;
    float v = (xv - mu) * rstd * gw[cg] + gb[cg];
    xn[idx] = v;
    lt[l*32 + c] = f2bf(v);
  }
  __syncthreads();
  int lr = tid >> 2, sl = tid & 3;
  uint4 u = *reinterpret_cast<uint4*>(&lt[lr*32 + sl*8]);
  size_t ob = ((size_t)bb*1024 + tile*64 + lr) * 1024 + g*32 + sl*8;
  *reinterpret_cast<uint4*>(&xnt[ob]) = u;
}

// ---------------- GEMM (r3-proven 2-phase 128x128): C = A[M][K] * Bt[N][K]^T ----------------
template<int MODE>
__global__ __launch_bounds__(256) void gemm_k(const unsigned short* __restrict__ A,
                                              const unsigned short* __restrict__ Bm,
                                              const float* __restrict__ bias,
                                              float* __restrict__ outf,
                                              unsigned short* __restrict__ qo,
                                              unsigned short* __restrict__ ko,
                                              unsigned short* __restrict__ vo){
  constexpr int MT = MODE ? 8 : 24;
  constexpr int CHUNK = MT * 8;
  __shared__ char sA[16384];
  __shared__ char sB[16384];
  const int tid = threadIdx.x;
  const int w = tid >> 6, ln = tid & 63, hi = ln >> 4, lo = ln & 15;
  const int wrow = w >> 1, wcol = w & 1;
  const int bxo = (int)blockIdx.x;
  const int bx = (bxo & 7) * CHUNK + (bxo >> 3);
  const int b = bx / (MT*8);
  const int rem = bx % (MT*8);
  const int mt = rem >> 3, nt = rem & 7;
  const char* Ag = (const char*)A + (size_t)mt*128*2048;
  const char* Bg = (const char*)Bm + ((size_t)b*1024 + nt*128)*2048;
  f32x4 acc[4][4] = {};
  for (int kk = 0; kk < 16; ++kk){
    #pragma unroll
    for (int i = 0; i < 4; ++i){
      int s = tid*16 + i*4096;
      int row = s >> 7;
      int byte = (s & 127) ^ ((row & 7) << 4);
      size_t off = (size_t)row*2048 + kk*128 + byte;
      load_lds16(Ag + off, sA + s);
      load_lds16(Bg + off, sB + s);
    }
    __syncthreads();
    #pragma unroll
    for (int ks = 0; ks < 2; ++ks){
      bf16x8 af[4], bq[4];
      #pragma unroll
      for (int mi = 0; mi < 4; ++mi){
        int row = wrow*64 + mi*16 + lo;
        af[mi] = *reinterpret_cast<const bf16x8*>(sA + row*128 + ((ks*64 + hi*16) ^ ((row & 7) << 4)));
      }
      #pragma unroll
      for (int ni = 0; ni < 4; ++ni){
        int row = wcol*64 + ni*16 + lo;
        bq[ni] = *reinterpret_cast<const bf16x8*>(sB + row*128 + ((ks*64 + hi*16) ^ ((row & 7) << 4)));
      }
      #pragma unroll
      for (int mi = 0; mi < 4; ++mi)
        #pragma unroll
        for (int ni = 0; ni < 4; ++ni)
          acc[mi][ni] = mfma16(af[mi], bq[ni], acc[mi][ni]);
    }
    __syncthreads();
  }
  if (MODE == 0){
    #pragma unroll
    for (int mi = 0; mi < 4; ++mi){
      const int o0 = mt*128 + wrow*64 + mi*16 + hi*4;
      const int hh = o0 / 192;
      const int rr = o0 % 192;
      const size_t hb = (size_t)b*16 + hh;
      float bv0 = bias[o0], bv1 = bias[o0+1], bv2 = bias[o0+2], bv3 = bias[o0+3];
      #pragma unroll
      for (int ni = 0; ni < 4; ++ni){
        const int l = nt*128 + wcol*64 + ni*16 + lo;
        if (rr < 64){
          ushort4 u;
          u.x = f2bf(acc[mi][ni][0] + bv0); u.y = f2bf(acc[mi][ni][1] + bv1);
          u.z = f2bf(acc[mi][ni][2] + bv2); u.w = f2bf(acc[mi][ni][3] + bv3);
          *reinterpret_cast<ushort4*>(qo + (hb*1024 + l)*64 + rr) = u;
        } else if (rr < 128){
          ushort4 u;
          u.x = f2bf(acc[mi][ni][0] + bv0); u.y = f2bf(acc[mi][ni][1] + bv1);
          u.z = f2bf(acc[mi][ni][2] + bv2); u.w = f2bf(acc[mi][ni][3] + bv3);
          *reinterpret_cast<ushort4*>(ko + (hb*1024 + l)*64 + (rr - 64)) = u;
        } else {
          const int d = rr - 128;
          vo[(hb*64 + d + 0)*1024 + l] = f2bf(acc[mi][ni][0] + bv0);
          vo[(hb*64 + d + 1)*1024 + l] = f2bf(acc[mi][ni][1] + bv1);
          vo[(hb*64 + d + 2)*1024 + l] = f2bf(acc[mi][ni][2] + bv2);
          vo[(hb*64 + d + 3)*1024 + l] = f2bf(acc[mi][ni][3] + bv3);
        }
      }
    }
  } else {
    #pragma unroll
    for (int mi = 0; mi < 4; ++mi){
      const int o0 = mt*128 + wrow*64 + mi*16 + hi*4;
      #pragma unroll
      for (int ni = 0; ni < 4; ++ni){
        const int l = nt*128 + wcol*64 + ni*16 + lo;
        #pragma unroll
        for (int r = 0; r < 4; ++r){
          size_t idx = ((size_t)b*1024 + o0 + r) * 1024 + l;
          outf[idx] += acc[mi][ni][r] + bias[o0 + r];
        }
      }
    }
  }
}

// ---------------- flash attention v5: r3 structure, 8 waves / 256 q rows, setprio ----------------
// Block = (b,h, 256 q rows), 8 waves x 32 q. KVBLK=64, dbuf K/V in LDS (staged once per
// 256 q instead of 128 -> staging/barrier cost halved per q-row). Swapped QK^T 32x32;
// in-register softmax; cvt_pk+permlane P path (validated r3 algebra, unchanged).
__global__ __launch_bounds__(512) void attn_k(const unsigned short* __restrict__ qt,
                                              const unsigned short* __restrict__ kt,
                                              const unsigned short* __restrict__ vt,
                                              unsigned short* __restrict__ ctx){
  __shared__ char sK[2][8192];
  __shared__ char sV[2][8192];
  __shared__ float sRed[8][32];
  const int tid = threadIdx.x;
  const int w = tid >> 6, ln = tid & 63;
  const int hi5 = ln >> 5, lo5 = ln & 31;
  const int bxo = (int)blockIdx.x;
  const int bx = (bxo & 7) * 64 + (bxo >> 3);    // XCD swizzle: 16 heads per XCD
  const int qb = bx & 3;
  const int bh = bx >> 2;                        // b*16 + h
  const unsigned short* qp = qt + ((size_t)bh*1024 + qb*256 + w*32 + lo5) * 64;
  bf16x8 qreg[4];
  #pragma unroll
  for (int d = 0; d < 4; ++d)
    qreg[d] = *reinterpret_cast<const bf16x8*>(qp + d*16 + hi5*8);
  const char* kg = (const char*)(kt + (size_t)bh*65536);
  const char* vg = (const char*)(vt + (size_t)bh*65536);
  f32x16 oa0 = {}, oa1 = {};
  float m = 0.f, lacc = 0.f;

  // 512 threads: K tile 8KB = 1 load/thread, V tile 8KB = 1 load/thread.
  auto STAGE = [&](int buf, int kb){
    int s = tid*16;
    int row = s >> 7;
    int byte = (s & 127) ^ ((row & 7) << 4);
    load_lds16(kg + (size_t)(kb*64 + row)*128 + byte, sK[buf] + s);
    load_lds16(vg + (size_t)row*2048 + kb*128 + byte, sV[buf] + s);
  };

  const float sc2 = 0.015625f * 1.44269504f;  // (1/64) * log2(e)

  STAGE(0, 0);
  asm volatile("s_waitcnt vmcnt(0)" ::: "memory");
  __builtin_amdgcn_s_barrier();

  for (int kb = 0; kb < 16; ++kb){
    const int cur = kb & 1;
    STAGE(cur ^ 1, (kb + 1) & 15);

    const char* kbase0 = sK[cur] + lo5*128;
    const char* kbase1 = sK[cur] + (32 + lo5)*128;
    const int ksw = (lo5 & 7) << 4;
    f32x16 s0 = {}, s1 = {};
    __builtin_amdgcn_s_setprio(1);
    #pragma unroll
    for (int d = 0; d < 4; ++d){
      int off = (d*32 + hi5*16) ^ ksw;
      bf16x8 ka = *reinterpret_cast<const bf16x8*>(kbase0 + off);
      bf16x8 kb8 = *reinterpret_cast<const bf16x8*>(kbase1 + off);
      s0 = mfma32(ka, qreg[d], s0);
      s1 = mfma32(kb8, qreg[d], s1);
    }
    __builtin_amdgcn_s_setprio(0);

    float t[16];
    #pragma unroll
    for (int i = 0; i < 16; ++i) t[i] = fmaxf(s0[i], s1[i]);
    #pragma unroll
    for (int st = 8; st; st >>= 1)
      #pragma unroll
      for (int i = 0; i < st; ++i) t[i] = fmaxf(t[i], t[i+st]);
    float mx = fmaxf(t[0], __shfl_xor(t[0], 32));
    float m2 = mx * sc2;

    if (__builtin_expect(__any(m2 > m + 8.f), 0)){
      float nm = fmaxf(m, m2);
      float corr = exp2_hw(m - nm);
      m = nm; lacc *= corr;
      sRed[w][lo5] = corr;
      __builtin_amdgcn_wave_barrier();
      #pragma unroll
      for (int r = 0; r < 16; ++r){
        float cc = sRed[w][(r & 3) + 8*(r >> 2) + 4*hi5];
        oa0[r] *= cc; oa1[r] *= cc;
      }
      __builtin_amdgcn_wave_barrier();
    }

    float ps[16];
    #pragma unroll
    for (int i = 0; i < 16; ++i){
      float p0 = exp2_hw(fmaf(s0[i], sc2, -m));
      float p1 = exp2_hw(fmaf(s1[i], sc2, -m));
      s0[i] = p0; s1[i] = p1;
      ps[i] = p0 + p1;
    }
    #pragma unroll
    for (int st = 8; st; st >>= 1)
      #pragma unroll
      for (int i = 0; i < st; ++i) ps[i] += ps[i+st];
    lacc += ps[0];   // linear: cross-half shuffle deferred to epilogue

    bf16x8 pa[4];
    #pragma unroll
    for (int sl = 0; sl < 4; ++sl){
      const int c0 = 2*(sl & 1), c1 = c0 + 1;
      unsigned w0, w1, w2, w3;
      if (sl < 2){
        w0 = cvtpk_bf16(s0[4*c0+0], s0[4*c0+1]);
        w1 = cvtpk_bf16(s0[4*c0+2], s0[4*c0+3]);
        w2 = cvtpk_bf16(s0[4*c1+0], s0[4*c1+1]);
        w3 = cvtpk_bf16(s0[4*c1+2], s0[4*c1+3]);
      } else {
        w0 = cvtpk_bf16(s1[4*c0+0], s1[4*c0+1]);
        w1 = cvtpk_bf16(s1[4*c0+2], s1[4*c0+3]);
        w2 = cvtpk_bf16(s1[4*c1+0], s1[4*c1+1]);
        w3 = cvtpk_bf16(s1[4*c1+2], s1[4*c1+3]);
      }
      permswap(w0, w2);
      permswap(w1, w3);
      u32x4 pc; pc.x = w0; pc.y = w1; pc.z = w2; pc.w = w3;
      pa[sl] = __builtin_bit_cast(bf16x8, pc);
    }

    const char* vb0 = sV[cur] + lo5*128;
    const char* vb1 = sV[cur] + (32 + lo5)*128;
    __builtin_amdgcn_s_setprio(1);
    #pragma unroll
    for (int sl = 0; sl < 4; ++sl){
      int off = (sl*32 + hi5*16) ^ ksw;
      bf16x8 v0 = *reinterpret_cast<const bf16x8*>(vb0 + off);
      bf16x8 v1 = *reinterpret_cast<const bf16x8*>(vb1 + off);
      oa0 = mfma32(pa[sl], v0, oa0);
      oa1 = mfma32(pa[sl], v1, oa1);
    }
    __builtin_amdgcn_s_setprio(0);

    asm volatile("s_waitcnt vmcnt(0)" ::: "memory");
    __builtin_amdgcn_s_barrier();
  }

  // --- epilogue: finish l (one cross-half shuffle), redistribute, write ctx^T ---
  float l = lacc + __shfl_xor(lacc, 32);
  sRed[w][lo5] = l;
  __builtin_amdgcn_wave_barrier();
  const int b = bh >> 4, h = bh & 15;
  #pragma unroll
  for (int r = 0; r < 16; ++r){
    int ql = (r & 3) + 8*(r >> 2) + 4*hi5;
    float inv = __builtin_amdgcn_rcpf(sRed[w][ql]);
    size_t rowb = ((size_t)b*1024 + qb*256 + w*32 + ql) * 1024 + h*64;
    ctx[rowb + lo5]      = f2bf(oa0[r] * inv);
    ctx[rowb + 32 + lo5] = f2bf(oa1[r] * inv);
  }
}

extern "C" void kernel_launch(void* const* d_in, const int* in_sizes, int n_in,
                              void* d_out, int out_size, void* d_ws, size_t ws_size,
                              hipStream_t stream) {
  (void)in_sizes; (void)n_in; (void)out_size; (void)ws_size;
  const float* x     = (const float*)d_in[0];
  const float* gn_w  = (const float*)d_in[1];
  const float* gn_b  = (const float*)d_in[2];
  const float* qkv_w = (const float*)d_in[3];
  const float* qkv_b = (const float*)d_in[4];
  const float* out_w = (const float*)d_in[5];
  const float* out_b = (const float*)d_in[6];
  // d_in[7] = qk_bias scalar: softmax(x+c)==softmax(x) -> no-op.
  float* out = (float*)d_out;
  char* ws = (char*)d_ws;
  unsigned short* xnt  = (unsigned short*)(ws);               // 16 MiB  xn^T  [b][l][c]
  unsigned short* qwb  = (unsigned short*)(ws + 16777216);    // 6 MiB   qkv_w bf16
  unsigned short* owb  = (unsigned short*)(ws + 23068672);    // 2 MiB   out_w bf16
  unsigned short* qt   = (unsigned short*)(ws + 25165824);    // 16 MiB  q [b][h][l][d]
  unsigned short* kt   = (unsigned short*)(ws + 41943040);    // 16 MiB  k [b][h][l][d]
  unsigned short* vs   = (unsigned short*)(ws + 58720256);    // 16 MiB  v [b][h][d][l]
  unsigned short* ctxt = (unsigned short*)(ws + 75497472);    // 16 MiB  ctx^T [b][l][c]
  float*          st   = (float*)(ws + 92274688);             // 2 KiB   GN stats

  wconv_k<<<512, 256, 0, stream>>>(qkv_w, qwb, 786432);
  wconv_k<<<512, 256, 0, stream>>>(out_w, owb, 262144);
  gn_stats_k<<<256, 256, 0, stream>>>(x, st);
  gn_norm_k<<<4096, 256, 0, stream>>>(x, gn_w, gn_b, st, out, xnt);
  gemm_k<0><<<1536, 256, 0, stream>>>(qwb, xnt, qkv_b, nullptr, qt, kt, vs);
  attn_k<<<512, 512, 0, stream>>>(qt, kt, vs, ctxt);
  gemm_k<1><<<512, 256, 0, stream>>>(owb, ctxt, out_b, out, nullptr, nullptr, nullptr);
}